// Round 4
// baseline (363.925 us; speedup 1.0000x reference)
//
#include <hip/hip_runtime.h>
#include <hip/hip_bf16.h>

// Shapes (fixed by the problem)
#define NB 2
#define NN 4096
#define NC 1024
#define NH 16
#define ND 64
#define NM (NB*NN)          // 8192 rows
#define NK 1024             // inner dim of both GEMMs
#define J_QKV 3072
// D^-0.5 * log2(e): folded into q at LN time so softmax runs in exp2 domain.
// Post-LN rows have ||q||,||k|| <= 8  =>  |score_exp2| <= 8*8*0.1803 = 11.54,
// so exp2(score) in [2^-11.6, 2^11.6]: fp32-safe with NO max subtraction.
#define QSCALE 0.18033688011112042f

typedef unsigned short u16;
typedef unsigned int   u32;
typedef __attribute__((ext_vector_type(8)))  __bf16 bf16x8;
typedef __attribute__((ext_vector_type(4)))  float  f32x4;
typedef __attribute__((ext_vector_type(16))) float  f32x16;

__device__ __forceinline__ u16 f2bf(float f) {
    unsigned int i = __builtin_bit_cast(unsigned int, f);
    unsigned int lsb = (i >> 16) & 1u;
    i += 0x7fffu + lsb;          // RNE
    return (u16)(i >> 16);
}
__device__ __forceinline__ float fast_exp2(float x) {
#if __has_builtin(__builtin_amdgcn_exp2f)
    return __builtin_amdgcn_exp2f(x);   // v_exp_f32 = 2^x
#else
    return exp2f(x);
#endif
}
// pack 2 fp32 -> 1 u32 of 2 bf16 (low = first arg).  NOTE: no builtin on
// gfx950 (m240); inline asm emits the single-instruction v_cvt_pk_bf16_f32.
__device__ __forceinline__ u32 pkbf(float a, float b) {
    u32 r;
    asm("v_cvt_pk_bf16_f32 %0, %1, %2" : "=v"(r) : "v"(a), "v"(b));
    return r;
}
// v_permlane32_swap_b32: returns {r0,r1} with r0 = {a.lo half, b.lo half},
// r1 = {a.hi half, b.hi half}. Used to assemble PV A-fragments in-register.
typedef struct { u32 x, y; } u32pair;
__device__ __forceinline__ u32pair swap32(u32 a, u32 b) {
#if __has_builtin(__builtin_amdgcn_permlane32_swap)
    auto r = __builtin_amdgcn_permlane32_swap((int)a, (int)b, false, false);
    u32pair o; o.x = (u32)r[0]; o.y = (u32)r[1]; return o;
#else
    const bool hi = (threadIdx.x & 32) != 0;
    u32 as = (u32)__shfl_xor((int)a, 32);
    u32 bs = (u32)__shfl_xor((int)b, 32);
    u32pair o; o.x = hi ? bs : a; o.y = hi ? b : as; return o;
#endif
}

// Async global->LDS 16B copy (global_load_lds_dwordx4).
__device__ __forceinline__ void glds16(const u16* g, u16* l) {
    __builtin_amdgcn_global_load_lds(
        (const __attribute__((address_space(1))) u32*)g,
        (__attribute__((address_space(3))) u32*)l, 16, 0, 0);
}

// ---------------------------------------------------------------------------
// fp32 -> bf16 elementwise convert (n multiple of 2048; 8 elems/thread).
// ---------------------------------------------------------------------------
__global__ __launch_bounds__(256) void cvt_bf16(
    const float* __restrict__ in, u16* __restrict__ out)
{
    const size_t i = ((size_t)blockIdx.x * 256 + threadIdx.x) * 8;
    const float4 a = *(const float4*)(in + i);
    const float4 b = *(const float4*)(in + i + 4);
    union { u16 h[8]; uint4 v; } u;
    u.h[0] = f2bf(a.x); u.h[1] = f2bf(a.y); u.h[2] = f2bf(a.z); u.h[3] = f2bf(a.w);
    u.h[4] = f2bf(b.x); u.h[5] = f2bf(b.y); u.h[6] = f2bf(b.z); u.h[7] = f2bf(b.w);
    *(uint4*)(out + i) = u.v;
}

// ---------------------------------------------------------------------------
// NT GEMM, m97 recipe: 128x128 tile, BK=32, global_load_lds(16B), 4 waves,
// each wave a 64x64 quadrant (4x4 grid of 16x16x32 MFMA tiles).
// LDS unpadded (glds lane-order constraint): As/Bs[128][32].
// MODE 0: fused per-head LayerNorm (q scaled by QSCALE) + scatter bf16 to
//         qkv ws [3][B][H][N][D].  Each wave's 64-col half == one head.
// MODE 1: fp32 linear [m][1024] (final output).
// ---------------------------------------------------------------------------
template<int MODE>
__global__ __launch_bounds__(256) void gemm_nt(
    const u16* __restrict__ A, const u16* __restrict__ W,
    const float* __restrict__ bias,
    const float* __restrict__ qw, const float* __restrict__ qb,
    const float* __restrict__ kw, const float* __restrict__ kb,
    void* __restrict__ outv)
{
    __shared__ __align__(16) u16 As[128][32];   // 8 KB
    __shared__ __align__(16) u16 Bs[128][32];   // 8 KB
    const int t = threadIdx.x;
    const int w = t >> 6, lane = t & 63;
    const int jb = blockIdx.x * 128;
    const int m0 = blockIdx.y * 128;
    const int wr = (w >> 1) * 64, wc = (w & 1) * 64;
    // staging: thread t covers rows t>>2 and 64+(t>>2), k-cols (t&3)*8..+7
    const int srow = t >> 2, skc = (t & 3) * 8;
    const u16* ap0 = A + (size_t)(m0 + srow) * NK + skc;
    const u16* ap1 = ap0 + (size_t)64 * NK;
    const u16* wp0 = W + (size_t)(jb + srow) * NK + skc;
    const u16* wp1 = wp0 + (size_t)64 * NK;
    u16* as0 = &As[srow][skc];      u16* as1 = &As[srow + 64][skc];
    u16* bs0 = &Bs[srow][skc];      u16* bs1 = &Bs[srow + 64][skc];
    const int fm = lane & 15, fk = 8 * (lane >> 4);
    f32x4 acc[4][4];
    #pragma unroll
    for (int i = 0; i < 4; ++i)
        #pragma unroll
        for (int j = 0; j < 4; ++j) acc[i][j] = (f32x4){0.f, 0.f, 0.f, 0.f};

    for (int kt = 0; kt < NK / 32; ++kt) {
        const int ko = kt * 32;
        glds16(ap0 + ko, as0);
        glds16(ap1 + ko, as1);
        glds16(wp0 + ko, bs0);
        glds16(wp1 + ko, bs1);
        __syncthreads();               // drains vmcnt (glds) before reads
        bf16x8 af[4], bfr[4];
        #pragma unroll
        for (int i = 0; i < 4; ++i) af[i]  = *(const bf16x8*)&As[wr + 16 * i + fm][fk];
        #pragma unroll
        for (int j = 0; j < 4; ++j) bfr[j] = *(const bf16x8*)&Bs[wc + 16 * j + fm][fk];
        #pragma unroll
        for (int i = 0; i < 4; ++i)
            #pragma unroll
            for (int j = 0; j < 4; ++j)
                acc[i][j] = __builtin_amdgcn_mfma_f32_16x16x32_bf16(af[i], bfr[j], acc[i][j], 0, 0, 0);
        __syncthreads();               // WAR before next kt's glds
    }
    // ---- epilogue ----
    const int c16 = lane & 15;
    float bv[4];
    #pragma unroll
    for (int j = 0; j < 4; ++j) bv[j] = bias[jb + wc + 16 * j + c16];
    #pragma unroll
    for (int i = 0; i < 4; ++i)
        #pragma unroll
        for (int j = 0; j < 4; ++j)
            #pragma unroll
            for (int r = 0; r < 4; ++r) acc[i][j][r] += bv[j];
    if (MODE == 0) {
        const int s = jb >> 10;            // 0=q, 1=k, 2=v (uniform per block)
        if (s < 2) {
            const float* lw = s ? kw : qw;
            const float* lb = s ? kb : qb;
            float lwv[4], lbv[4];
            #pragma unroll
            for (int j = 0; j < 4; ++j) {
                lwv[j] = lw[16 * j + c16]; lbv[j] = lb[16 * j + c16];
            }
            #pragma unroll
            for (int i = 0; i < 4; ++i)
                #pragma unroll
                for (int r = 0; r < 4; ++r) {
                    float sum = acc[i][0][r] + acc[i][1][r] + acc[i][2][r] + acc[i][3][r];
                    #pragma unroll
                    for (int off = 1; off < 16; off <<= 1) sum += __shfl_xor(sum, off);
                    const float mu = sum * (1.0f / 64.0f);
                    float v2 = 0.f;
                    #pragma unroll
                    for (int j = 0; j < 4; ++j) { const float dd = acc[i][j][r] - mu; v2 += dd * dd; }
                    #pragma unroll
                    for (int off = 1; off < 16; off <<= 1) v2 += __shfl_xor(v2, off);
                    const float rstd = rsqrtf(v2 * (1.0f / 64.0f) + 1e-5f);
                    #pragma unroll
                    for (int j = 0; j < 4; ++j) {
                        float y = (acc[i][j][r] - mu) * rstd * lwv[j] + lbv[j];
                        if (s == 0) y *= QSCALE;
                        acc[i][j][r] = y;
                    }
                }
        }
        u16* out = (u16*)outv;
        const int r0 = 4 * (lane >> 4);
        #pragma unroll
        for (int j = 0; j < 4; ++j) {
            const int col = jb + wc + 16 * j + c16;
            const int ss = col >> 10, hh = (col >> 6) & 15, d = col & 63;
            #pragma unroll
            for (int i = 0; i < 4; ++i)
                #pragma unroll
                for (int r = 0; r < 4; ++r) {
                    const int row = m0 + wr + 16 * i + r0 + r;
                    const int b = row >> 12, n = row & 4095;
                    out[((((size_t)ss * NB + b) * NH + hh) * NN + n) * ND + d] = f2bf(acc[i][j][r]);
                }
        }
    } else {
        float* out = (float*)outv;
        const int r0 = 4 * (lane >> 4);
        #pragma unroll
        for (int i = 0; i < 4; ++i)
            #pragma unroll
            for (int r = 0; r < 4; ++r) {
                const int row = m0 + wr + 16 * i + r0 + r;
                #pragma unroll
                for (int j = 0; j < 4; ++j)
                    out[(size_t)row * NC + jb + wc + 16 * j + c16] = acc[i][j][r];
            }
    }
}

// ---------------------------------------------------------------------------
// MFMA flash attention, fixed-shift softmax, in-register P (no LDS round-trip).
// Block = 4 waves; wave = 64 q-rows (2 x 32-row q-sets); K-blocks of 64 keys.
// DOUBLE-BUFFERED Ks/Vt: ONE barrier per iteration (T14 split: global loads
// issued at iter top, ds_writes to next buffer after compute).
// Per-iteration pipeline: QK(s0) -> QK(s1) -> SM(s0) -> PV(s0) -> SM(s1)
// -> PV(s1): softmax VALU/TRANS issues under in-flight MFMAs.
// Swapped QK^T: S^T = mfma(K, Q) so lane l holds P for q = l&31, keys
// (r&3)+8*(r>>2)+4*(l>>5).  PV A-frags assembled via asm cvt_pk + permlane.
// ---------------------------------------------------------------------------
__global__ __launch_bounds__(256, 2) void attn_mfma(
    const u16* __restrict__ qkv, u16* __restrict__ aout)
{
    __shared__ __align__(16) u16 Ks[2][64][72];   // K-block   [key][d]   18.4 KB
    __shared__ __align__(16) u16 Vt[2][64][72];   // V-block^T [d][key]   18.4 KB
    const int bid  = blockIdx.x;
    const int qblk = bid & 15;
    const int bh   = bid >> 4;
    const int b = bh >> 4, hh = bh & 15;
    const size_t plane = (size_t)NB * NH * NN * ND;
    const size_t base  = ((size_t)(b * NH + hh)) * NN * ND;
    const u16* qp = qkv + base;
    const u16* kp = qkv + plane + base;
    const u16* vp = qkv + 2 * plane + base;
    const int t = threadIdx.x, w = t >> 6, lane = t & 63;
    const int half = lane >> 5, m32 = lane & 31;
    const int q0 = qblk * 256 + 64 * w;           // this wave's 64 q-rows

    // Q as B-operand (col = q = lane&31, k = d)
    bf16x8 qf[2][4];
    #pragma unroll
    for (int s = 0; s < 2; ++s) {
        const u16* qrow = qp + (size_t)(q0 + 32 * s + m32) * ND + 8 * half;
        #pragma unroll
        for (int kt = 0; kt < 4; ++kt) qf[s][kt] = *(const bf16x8*)(qrow + 16 * kt);
    }
    f32x16 O[2][2], z;
    #pragma unroll
    for (int r = 0; r < 16; ++r) { O[0][0][r] = 0.f; O[0][1][r] = 0.f;
                                   O[1][0][r] = 0.f; O[1][1][r] = 0.f; z[r] = 0.f; }
    float lpart[2] = {0.f, 0.f};    // lane-local softmax denominators (half keys each)

    const int dgK = 16 * w;                     // K staging: key=lane, 16 d/thread
    const int kp2 = t & 31, dgV = (t >> 5) * 8; // V staging: 2 keys x 8 d/thread
    const u16* ksrc = kp + (size_t)lane * ND + dgK;
    const u16* vsrc = vp + (size_t)(2 * kp2) * ND + dgV;

    uint4 kr0, kr1, vre, vro;                   // staged regs for next K-block
    // prologue: stage block 0 into buffer 0
    kr0 = *(const uint4*)(ksrc);
    kr1 = *(const uint4*)(ksrc + 8);
    vre = *(const uint4*)(vsrc);
    vro = *(const uint4*)(vsrc + ND);
    {
        *(uint4*)&Ks[0][lane][dgK]     = kr0;
        *(uint4*)&Ks[0][lane][dgK + 8] = kr1;
        const u32* ew = (const u32*)&vre;
        const u32* ow = (const u32*)&vro;
        #pragma unroll
        for (int d = 0; d < 4; ++d) {       // v_perm_b32 pair-pack transpose
            u32 lo = __builtin_amdgcn_perm(ow[d], ew[d], 0x05040100u);
            u32 hi = __builtin_amdgcn_perm(ow[d], ew[d], 0x07060302u);
            *(u32*)&Vt[0][dgV + 2 * d][2 * kp2]     = lo;
            *(u32*)&Vt[0][dgV + 2 * d + 1][2 * kp2] = hi;
        }
    }
    __syncthreads();

    union W8 { u32 wd[4]; bf16x8 f; };

    for (int kb = 0; kb < NN / 64; ++kb) {
        const int cur = kb & 1, nxt = cur ^ 1;
        const bool more = (kb + 1) < (NN / 64);
        if (more) {   // issue next block's global loads early (hide under compute)
            const u16* ks2 = ksrc + (size_t)(kb + 1) * 64 * ND;
            kr0 = *(const uint4*)ks2;
            kr1 = *(const uint4*)(ks2 + 8);
            const u16* vs2 = vsrc + (size_t)(kb + 1) * 64 * ND;
            vre = *(const uint4*)vs2;
            vro = *(const uint4*)(vs2 + ND);
        }
        // ---- QK (s0): S^T = K . Q^T, col=lane&31=q, row=key pattern ----
        f32x16 sT0[2], sT1[2];
        __builtin_amdgcn_s_setprio(1);
        {
            bf16x8 k0 = *(const bf16x8*)&Ks[cur][m32][8 * half];
            bf16x8 k1 = *(const bf16x8*)&Ks[cur][32 + m32][8 * half];
            sT0[0] = __builtin_amdgcn_mfma_f32_32x32x16_bf16(k0, qf[0][0], z, 0, 0, 0);
            sT0[1] = __builtin_amdgcn_mfma_f32_32x32x16_bf16(k1, qf[0][0], z, 0, 0, 0);
        }
        #pragma unroll
        for (int kt = 1; kt < 4; ++kt) {
            bf16x8 k0 = *(const bf16x8*)&Ks[cur][m32][16 * kt + 8 * half];
            bf16x8 k1 = *(const bf16x8*)&Ks[cur][32 + m32][16 * kt + 8 * half];
            sT0[0] = __builtin_amdgcn_mfma_f32_32x32x16_bf16(k0, qf[0][kt], sT0[0], 0, 0, 0);
            sT0[1] = __builtin_amdgcn_mfma_f32_32x32x16_bf16(k1, qf[0][kt], sT0[1], 0, 0, 0);
        }
        // ---- QK (s1): issues while sT0 chain drains ----
        {
            bf16x8 k0 = *(const bf16x8*)&Ks[cur][m32][8 * half];
            bf16x8 k1 = *(const bf16x8*)&Ks[cur][32 + m32][8 * half];
            sT1[0] = __builtin_amdgcn_mfma_f32_32x32x16_bf16(k0, qf[1][0], z, 0, 0, 0);
            sT1[1] = __builtin_amdgcn_mfma_f32_32x32x16_bf16(k1, qf[1][0], z, 0, 0, 0);
        }
        #pragma unroll
        for (int kt = 1; kt < 4; ++kt) {
            bf16x8 k0 = *(const bf16x8*)&Ks[cur][m32][16 * kt + 8 * half];
            bf16x8 k1 = *(const bf16x8*)&Ks[cur][32 + m32][16 * kt + 8 * half];
            sT1[0] = __builtin_amdgcn_mfma_f32_32x32x16_bf16(k0, qf[1][kt], sT1[0], 0, 0, 0);
            sT1[1] = __builtin_amdgcn_mfma_f32_32x32x16_bf16(k1, qf[1][kt], sT1[1], 0, 0, 0);
        }
        __builtin_amdgcn_s_setprio(0);
        // ---- SM (s0): exp2 + cvt_pk + permlane, under QK(s1) MFMAs ----
        W8 pa0[4], pa1[4];
        {
            float ss0 = 0.f, ss1 = 0.f;
            #pragma unroll
            for (int kh = 0; kh < 2; ++kh) {
                float p[16];
                #pragma unroll
                for (int r = 0; r < 16; ++r) p[r] = fast_exp2(sT0[kh][r]);
                #pragma unroll
                for (int r = 0; r < 8; ++r) { ss0 += p[r]; ss1 += p[8 + r]; }
                u32 c[4][2];
                #pragma unroll
                for (int g = 0; g < 4; ++g) {
                    c[g][0] = pkbf(p[4 * g + 0], p[4 * g + 1]);
                    c[g][1] = pkbf(p[4 * g + 2], p[4 * g + 3]);
                }
                #pragma unroll
                for (int par = 0; par < 2; ++par) {
                    u32pair wA = swap32(c[2 * par][0], c[2 * par + 1][0]);
                    u32pair wB = swap32(c[2 * par][1], c[2 * par + 1][1]);
                    const int kt = 2 * kh + par;
                    pa0[kt].wd[0] = wA.x;   // keys +0,+1 (from low-half lane)
                    pa0[kt].wd[1] = wB.x;   // keys +2,+3
                    pa0[kt].wd[2] = wA.y;   // keys +4,+5 (from high-half lane)
                    pa0[kt].wd[3] = wB.y;   // keys +6,+7
                }
            }
            lpart[0] += ss0 + ss1;
        }
        // ---- PV (s0) ----
        __builtin_amdgcn_s_setprio(1);
        #pragma unroll
        for (int kt = 0; kt < 4; ++kt) {
            bf16x8 v0 = *(const bf16x8*)&Vt[cur][m32][16 * kt + 8 * half];
            bf16x8 v1 = *(const bf16x8*)&Vt[cur][32 + m32][16 * kt + 8 * half];
            O[0][0] = __builtin_amdgcn_mfma_f32_32x32x16_bf16(pa0[kt].f, v0, O[0][0], 0, 0, 0);
            O[0][1] = __builtin_amdgcn_mfma_f32_32x32x16_bf16(pa0[kt].f, v1, O[0][1], 0, 0, 0);
        }
        __builtin_amdgcn_s_setprio(0);
        // ---- SM (s1): under PV(s0) MFMAs ----
        {
            float ss0 = 0.f, ss1 = 0.f;
            #pragma unroll
            for (int kh = 0; kh < 2; ++kh) {
                float p[16];
                #pragma unroll
                for (int r = 0; r < 16; ++r) p[r] = fast_exp2(sT1[kh][r]);
                #pragma unroll
                for (int r = 0; r < 8; ++r) { ss0 += p[r]; ss1 += p[8 + r]; }
                u32 c[4][2];
                #pragma unroll
                for (int g = 0; g < 4; ++g) {
                    c[g][0] = pkbf(p[4 * g + 0], p[4 * g + 1]);
                    c[g][1] = pkbf(p[4 * g + 2], p[4 * g + 3]);
                }
                #pragma unroll
                for (int par = 0; par < 2; ++par) {
                    u32pair wA = swap32(c[2 * par][0], c[2 * par + 1][0]);
                    u32pair wB = swap32(c[2 * par][1], c[2 * par + 1][1]);
                    const int kt = 2 * kh + par;
                    pa1[kt].wd[0] = wA.x;
                    pa1[kt].wd[1] = wB.x;
                    pa1[kt].wd[2] = wA.y;
                    pa1[kt].wd[3] = wB.y;
                }
            }
            lpart[1] += ss0 + ss1;
        }
        // ---- PV (s1) ----
        __builtin_amdgcn_s_setprio(1);
        #pragma unroll
        for (int kt = 0; kt < 4; ++kt) {
            bf16x8 v0 = *(const bf16x8*)&Vt[cur][m32][16 * kt + 8 * half];
            bf16x8 v1 = *(const bf16x8*)&Vt[cur][32 + m32][16 * kt + 8 * half];
            O[1][0] = __builtin_amdgcn_mfma_f32_32x32x16_bf16(pa1[kt].f, v0, O[1][0], 0, 0, 0);
            O[1][1] = __builtin_amdgcn_mfma_f32_32x32x16_bf16(pa1[kt].f, v1, O[1][1], 0, 0, 0);
        }
        __builtin_amdgcn_s_setprio(0);
        // ---- stage next block into nxt buffer; ONE barrier per iteration ----
        if (more) {
            *(uint4*)&Ks[nxt][lane][dgK]     = kr0;
            *(uint4*)&Ks[nxt][lane][dgK + 8] = kr1;
            const u32* ew = (const u32*)&vre;
            const u32* ow = (const u32*)&vro;
            #pragma unroll
            for (int d = 0; d < 4; ++d) {
                u32 lo = __builtin_amdgcn_perm(ow[d], ew[d], 0x05040100u);
                u32 hi = __builtin_amdgcn_perm(ow[d], ew[d], 0x07060302u);
                *(u32*)&Vt[nxt][dgV + 2 * d][2 * kp2]     = lo;
                *(u32*)&Vt[nxt][dgV + 2 * d + 1][2 * kp2] = hi;
            }
            __syncthreads();   // nxt writes visible; cur reads done for all waves
        }
    }
    // epilogue: denominator = own half-sum + other half (lanes l, l+32 share q),
    // then redistribute to O's row layout via shfl.
    #pragma unroll
    for (int s = 0; s < 2; ++s) {
        const float tot = lpart[s] + __shfl_xor(lpart[s], 32);  // at lane l: q=l&31
        #pragma unroll
        for (int r = 0; r < 16; ++r) {
            const int qq = (r & 3) + 8 * (r >> 2) + 4 * half;   // O-row for this reg
            const float inv = 1.0f / __shfl(tot, qq);           // lane qq holds q=qq
            const int row = q0 + 32 * s + qq;
            u16* dst = aout + ((size_t)(b * NN + row)) * NC + hh * 64;
            dst[m32]      = f2bf(O[s][0][r] * inv);
            dst[32 + m32] = f2bf(O[s][1][r] * inv);
        }
    }
}

// ---------------------------------------------------------------------------
extern "C" void kernel_launch(void* const* d_in, const int* in_sizes, int n_in,
                              void* d_out, int out_size, void* d_ws, size_t ws_size,
                              hipStream_t stream) {
    const float* x     = (const float*)d_in[0];
    const float* qkv_w = (const float*)d_in[1];
    const float* qkv_b = (const float*)d_in[2];
    const float* q_nw  = (const float*)d_in[3];
    const float* q_nb  = (const float*)d_in[4];
    const float* k_nw  = (const float*)d_in[5];
    const float* k_nb  = (const float*)d_in[6];
    const float* p_w   = (const float*)d_in[7];
    const float* p_b   = (const float*)d_in[8];
    float* out = (float*)d_out;               // fp32 output
    // ws layout (u16 elements):
    //   qkv   [3][B][H][N][D]                              48 MB
    //   x_bf / attn_o (aliased: x_bf dead after QKV GEMM)  16.8 MB
    //   w_bf  qkv_w bf16                                    6.3 MB
    //   pw_bf proj_w bf16                                   2.1 MB
    u16* qkv    = (u16*)d_ws;
    u16* x_bf   = qkv + (size_t)3 * NB * NH * NN * ND;
    u16* attn_o = x_bf;                        // alias
    u16* w_bf   = x_bf + (size_t)NM * NC;
    u16* pw_bf  = w_bf + (size_t)J_QKV * NK;

    cvt_bf16<<<(NM * NC) / 2048, 256, 0, stream>>>(x, x_bf);
    cvt_bf16<<<(J_QKV * NK) / 2048, 256, 0, stream>>>(qkv_w, w_bf);
    cvt_bf16<<<(NC * NK) / 2048, 256, 0, stream>>>(p_w, pw_bf);

    gemm_nt<0><<<dim3(J_QKV / 128, NM / 128), 256, 0, stream>>>(
        x_bf, w_bf, qkv_b, q_nw, q_nb, k_nw, k_nb, qkv);
    attn_mfma<<<NB * NH * (NN / 256), 256, 0, stream>>>(qkv, attn_o);
    gemm_nt<1><<<dim3(NC / 128, NM / 128), 256, 0, stream>>>(
        attn_o, pw_bf, p_b, q_nw, q_nb, k_nw, k_nb, out);
}

// Round 6
// 331.770 us; speedup vs baseline: 1.0969x; 1.0969x over previous
//
#include <hip/hip_runtime.h>
#include <hip/hip_bf16.h>

// Shapes (fixed by the problem)
#define NB 2
#define NN 4096
#define NC 1024
#define NH 16
#define ND 64
#define NM (NB*NN)          // 8192 rows
#define NK 1024             // inner dim of both GEMMs
#define J_QKV 3072
// D^-0.5 * log2(e): folded into q at LN time so softmax runs in exp2 domain.
// Post-LN rows have ||q||,||k|| <= 8  =>  |score_exp2| <= 8*8*0.1803 = 11.54,
// so exp2(score) in [2^-11.6, 2^11.6]: fp32-safe with NO max subtraction.
#define QSCALE 0.18033688011112042f

typedef unsigned short u16;
typedef unsigned int   u32;
typedef __attribute__((ext_vector_type(8)))  __bf16 bf16x8;
typedef __attribute__((ext_vector_type(4)))  float  f32x4;
typedef __attribute__((ext_vector_type(16))) float  f32x16;

__device__ __forceinline__ u16 f2bf(float f) {
    unsigned int i = __builtin_bit_cast(unsigned int, f);
    unsigned int lsb = (i >> 16) & 1u;
    i += 0x7fffu + lsb;          // RNE
    return (u16)(i >> 16);
}
__device__ __forceinline__ float fast_exp2(float x) {
#if __has_builtin(__builtin_amdgcn_exp2f)
    return __builtin_amdgcn_exp2f(x);   // v_exp_f32 = 2^x
#else
    return exp2f(x);
#endif
}
// pack 2 fp32 -> 1 u32 of 2 bf16 (low = first arg).  NOTE: no builtin on
// gfx950 (m240); inline asm emits the single-instruction v_cvt_pk_bf16_f32.
__device__ __forceinline__ u32 pkbf(float a, float b) {
    u32 r;
    asm("v_cvt_pk_bf16_f32 %0, %1, %2" : "=v"(r) : "v"(a), "v"(b));
    return r;
}
// v_permlane32_swap_b32: returns {r0,r1} with r0 = {a.lo half, b.lo half},
// r1 = {a.hi half, b.hi half}. Used to assemble PV A-fragments in-register.
typedef struct { u32 x, y; } u32pair;
__device__ __forceinline__ u32pair swap32(u32 a, u32 b) {
#if __has_builtin(__builtin_amdgcn_permlane32_swap)
    auto r = __builtin_amdgcn_permlane32_swap((int)a, (int)b, false, false);
    u32pair o; o.x = (u32)r[0]; o.y = (u32)r[1]; return o;
#else
    const bool hi = (threadIdx.x & 32) != 0;
    u32 as = (u32)__shfl_xor((int)a, 32);
    u32 bs = (u32)__shfl_xor((int)b, 32);
    u32pair o; o.x = hi ? bs : a; o.y = hi ? b : as; return o;
#endif
}

// Async global->LDS 16B copy (global_load_lds_dwordx4).
__device__ __forceinline__ void glds16(const u16* g, u16* l) {
    __builtin_amdgcn_global_load_lds(
        (const __attribute__((address_space(1))) u32*)g,
        (__attribute__((address_space(3))) u32*)l, 16, 0, 0);
}

// ---------------------------------------------------------------------------
// fp32 -> bf16 elementwise convert (n multiple of 2048; 8 elems/thread).
// ---------------------------------------------------------------------------
__global__ __launch_bounds__(256) void cvt_bf16(
    const float* __restrict__ in, u16* __restrict__ out)
{
    const size_t i = ((size_t)blockIdx.x * 256 + threadIdx.x) * 8;
    const float4 a = *(const float4*)(in + i);
    const float4 b = *(const float4*)(in + i + 4);
    union { u16 h[8]; uint4 v; } u;
    u.h[0] = f2bf(a.x); u.h[1] = f2bf(a.y); u.h[2] = f2bf(a.z); u.h[3] = f2bf(a.w);
    u.h[4] = f2bf(b.x); u.h[5] = f2bf(b.y); u.h[6] = f2bf(b.z); u.h[7] = f2bf(b.w);
    *(uint4*)(out + i) = u.v;
}

// ---------------------------------------------------------------------------
// NT GEMM, m97 recipe + BK=64 + XCD swizzle:
// - 128x128 tile, 4 waves, each wave a 64x64 quadrant (4x4 of 16x16x32 MFMA).
// - BK=64 as TWO proven [128][32] LDS arrays per input (lo/hi k-halves):
//   identical glds16 lane-order layout, 16 barrier-pairs instead of 32.
// - 1D grid with bijective XCD-chunk swizzle (gridDim.x % 8 == 0): each XCD
//   owns a contiguous run of blocks -> A-panel hits its L2 once, not 8x.
// MODE 0: fused per-head LayerNorm (q scaled by QSCALE) + scatter bf16 to
//         qkv ws [3][B][H][N][D].  Each wave's 64-col half == one head.
// MODE 1: fp32 linear [m][1024] (final output).
// NJB = number of 128-wide column tiles (24 for MODE 0, 8 for MODE 1).
// ---------------------------------------------------------------------------
template<int MODE, int NJB>
__global__ __launch_bounds__(256, 3) void gemm_nt(
    const u16* __restrict__ A, const u16* __restrict__ W,
    const float* __restrict__ bias,
    const float* __restrict__ qw, const float* __restrict__ qb,
    const float* __restrict__ kw, const float* __restrict__ kb,
    void* __restrict__ outv)
{
    __shared__ __align__(16) u16 AsL[128][32];  // 8 KB  (k-cols ko..ko+31)
    __shared__ __align__(16) u16 AsH[128][32];  // 8 KB  (k-cols ko+32..ko+63)
    __shared__ __align__(16) u16 BsL[128][32];  // 8 KB
    __shared__ __align__(16) u16 BsH[128][32];  // 8 KB
    const int t = threadIdx.x;
    const int w = t >> 6, lane = t & 63;
    // XCD-chunked bijective swizzle (requires gridDim.x % 8 == 0; 1536/512 ok)
    const int nb  = blockIdx.x;
    const int cpx = gridDim.x >> 3;
    const int nb2 = (nb & 7) * cpx + (nb >> 3);
    const int jb  = (nb2 % NJB) * 128;
    const int m0  = (nb2 / NJB) * 128;
    const int wr = (w >> 1) * 64, wc = (w & 1) * 64;
    // staging: thread t covers rows t>>2 and 64+(t>>2), k-cols (t&3)*8..+7
    // (dest LDS byte = 16*t within each array: glds16 lane-order constraint)
    const int srow = t >> 2, skc = (t & 3) * 8;
    const u16* ap0 = A + (size_t)(m0 + srow) * NK + skc;
    const u16* ap1 = ap0 + (size_t)64 * NK;
    const u16* wp0 = W + (size_t)(jb + srow) * NK + skc;
    const u16* wp1 = wp0 + (size_t)64 * NK;
    u16* asl0 = &AsL[srow][skc];    u16* asl1 = &AsL[srow + 64][skc];
    u16* ash0 = &AsH[srow][skc];    u16* ash1 = &AsH[srow + 64][skc];
    u16* bsl0 = &BsL[srow][skc];    u16* bsl1 = &BsL[srow + 64][skc];
    u16* bsh0 = &BsH[srow][skc];    u16* bsh1 = &BsH[srow + 64][skc];
    const int fm = lane & 15, fk = 8 * (lane >> 4);
    f32x4 acc[4][4];
    #pragma unroll
    for (int i = 0; i < 4; ++i)
        #pragma unroll
        for (int j = 0; j < 4; ++j) acc[i][j] = (f32x4){0.f, 0.f, 0.f, 0.f};

    for (int kt = 0; kt < NK / 64; ++kt) {
        const int ko = kt * 64;
        glds16(ap0 + ko, asl0);
        glds16(ap1 + ko, asl1);
        glds16(ap0 + ko + 32, ash0);
        glds16(ap1 + ko + 32, ash1);
        glds16(wp0 + ko, bsl0);
        glds16(wp1 + ko, bsl1);
        glds16(wp0 + ko + 32, bsh0);
        glds16(wp1 + ko + 32, bsh1);
        __syncthreads();               // drains vmcnt (glds) before reads
        {   // ---- lo k-half: cols ko..ko+31 ----
            bf16x8 af[4], bfr[4];
            #pragma unroll
            for (int i = 0; i < 4; ++i) af[i]  = *(const bf16x8*)&AsL[wr + 16 * i + fm][fk];
            #pragma unroll
            for (int j = 0; j < 4; ++j) bfr[j] = *(const bf16x8*)&BsL[wc + 16 * j + fm][fk];
            #pragma unroll
            for (int i = 0; i < 4; ++i)
                #pragma unroll
                for (int j = 0; j < 4; ++j)
                    acc[i][j] = __builtin_amdgcn_mfma_f32_16x16x32_bf16(af[i], bfr[j], acc[i][j], 0, 0, 0);
        }
        {   // ---- hi k-half: cols ko+32..ko+63 ----
            bf16x8 af[4], bfr[4];
            #pragma unroll
            for (int i = 0; i < 4; ++i) af[i]  = *(const bf16x8*)&AsH[wr + 16 * i + fm][fk];
            #pragma unroll
            for (int j = 0; j < 4; ++j) bfr[j] = *(const bf16x8*)&BsH[wc + 16 * j + fm][fk];
            #pragma unroll
            for (int i = 0; i < 4; ++i)
                #pragma unroll
                for (int j = 0; j < 4; ++j)
                    acc[i][j] = __builtin_amdgcn_mfma_f32_16x16x32_bf16(af[i], bfr[j], acc[i][j], 0, 0, 0);
        }
        __syncthreads();               // WAR before next kt's glds
    }
    // ---- epilogue ----
    const int c16 = lane & 15;
    float bv[4];
    #pragma unroll
    for (int j = 0; j < 4; ++j) bv[j] = bias[jb + wc + 16 * j + c16];
    #pragma unroll
    for (int i = 0; i < 4; ++i)
        #pragma unroll
        for (int j = 0; j < 4; ++j)
            #pragma unroll
            for (int r = 0; r < 4; ++r) acc[i][j][r] += bv[j];
    if (MODE == 0) {
        const int s = jb >> 10;            // 0=q, 1=k, 2=v (uniform per block)
        if (s < 2) {
            const float* lw = s ? kw : qw;
            const float* lb = s ? kb : qb;
            float lwv[4], lbv[4];
            #pragma unroll
            for (int j = 0; j < 4; ++j) {
                lwv[j] = lw[16 * j + c16]; lbv[j] = lb[16 * j + c16];
            }
            #pragma unroll
            for (int i = 0; i < 4; ++i)
                #pragma unroll
                for (int r = 0; r < 4; ++r) {
                    float sum = acc[i][0][r] + acc[i][1][r] + acc[i][2][r] + acc[i][3][r];
                    #pragma unroll
                    for (int off = 1; off < 16; off <<= 1) sum += __shfl_xor(sum, off);
                    const float mu = sum * (1.0f / 64.0f);
                    float v2 = 0.f;
                    #pragma unroll
                    for (int j = 0; j < 4; ++j) { const float dd = acc[i][j][r] - mu; v2 += dd * dd; }
                    #pragma unroll
                    for (int off = 1; off < 16; off <<= 1) v2 += __shfl_xor(v2, off);
                    const float rstd = rsqrtf(v2 * (1.0f / 64.0f) + 1e-5f);
                    #pragma unroll
                    for (int j = 0; j < 4; ++j) {
                        float y = (acc[i][j][r] - mu) * rstd * lwv[j] + lbv[j];
                        if (s == 0) y *= QSCALE;
                        acc[i][j][r] = y;
                    }
                }
        }
        u16* out = (u16*)outv;
        const int r0 = 4 * (lane >> 4);
        #pragma unroll
        for (int j = 0; j < 4; ++j) {
            const int col = jb + wc + 16 * j + c16;
            const int ss = col >> 10, hh = (col >> 6) & 15, d = col & 63;
            #pragma unroll
            for (int i = 0; i < 4; ++i)
                #pragma unroll
                for (int r = 0; r < 4; ++r) {
                    const int row = m0 + wr + 16 * i + r0 + r;
                    const int b = row >> 12, n = row & 4095;
                    out[((((size_t)ss * NB + b) * NH + hh) * NN + n) * ND + d] = f2bf(acc[i][j][r]);
                }
        }
    } else {
        float* out = (float*)outv;
        const int r0 = 4 * (lane >> 4);
        #pragma unroll
        for (int i = 0; i < 4; ++i)
            #pragma unroll
            for (int r = 0; r < 4; ++r) {
                const int row = m0 + wr + 16 * i + r0 + r;
                #pragma unroll
                for (int j = 0; j < 4; ++j)
                    out[(size_t)row * NC + jb + wc + 16 * j + c16] = acc[i][j][r];
            }
    }
}

// ---------------------------------------------------------------------------
// MFMA flash attention (R4-verified version, reverted verbatim).
// Block = 4 waves; wave = 64 q-rows (2 x 32-row q-sets); K-blocks of 64 keys.
// DOUBLE-BUFFERED Ks/Vt: ONE barrier per iteration (T14 split: global loads
// issued at iter top, ds_writes to next buffer after compute).
// Per-iteration pipeline: QK(s0) -> QK(s1) -> SM(s0) -> PV(s0) -> SM(s1)
// -> PV(s1): softmax VALU/TRANS issues under in-flight MFMAs.
// Swapped QK^T: S^T = mfma(K, Q) so lane l holds P for q = l&31, keys
// (r&3)+8*(r>>2)+4*(l>>5).  PV A-frags assembled via asm cvt_pk + permlane.
// ---------------------------------------------------------------------------
__global__ __launch_bounds__(256, 2) void attn_mfma(
    const u16* __restrict__ qkv, u16* __restrict__ aout)
{
    __shared__ __align__(16) u16 Ks[2][64][72];   // K-block   [key][d]   18.4 KB
    __shared__ __align__(16) u16 Vt[2][64][72];   // V-block^T [d][key]   18.4 KB
    const int bid  = blockIdx.x;
    const int qblk = bid & 15;
    const int bh   = bid >> 4;
    const int b = bh >> 4, hh = bh & 15;
    const size_t plane = (size_t)NB * NH * NN * ND;
    const size_t base  = ((size_t)(b * NH + hh)) * NN * ND;
    const u16* qp = qkv + base;
    const u16* kp = qkv + plane + base;
    const u16* vp = qkv + 2 * plane + base;
    const int t = threadIdx.x, w = t >> 6, lane = t & 63;
    const int half = lane >> 5, m32 = lane & 31;
    const int q0 = qblk * 256 + 64 * w;           // this wave's 64 q-rows

    // Q as B-operand (col = q = lane&31, k = d)
    bf16x8 qf[2][4];
    #pragma unroll
    for (int s = 0; s < 2; ++s) {
        const u16* qrow = qp + (size_t)(q0 + 32 * s + m32) * ND + 8 * half;
        #pragma unroll
        for (int kt = 0; kt < 4; ++kt) qf[s][kt] = *(const bf16x8*)(qrow + 16 * kt);
    }
    f32x16 O[2][2], z;
    #pragma unroll
    for (int r = 0; r < 16; ++r) { O[0][0][r] = 0.f; O[0][1][r] = 0.f;
                                   O[1][0][r] = 0.f; O[1][1][r] = 0.f; z[r] = 0.f; }
    float lpart[2] = {0.f, 0.f};    // lane-local softmax denominators (half keys each)

    const int dgK = 16 * w;                     // K staging: key=lane, 16 d/thread
    const int kp2 = t & 31, dgV = (t >> 5) * 8; // V staging: 2 keys x 8 d/thread
    const u16* ksrc = kp + (size_t)lane * ND + dgK;
    const u16* vsrc = vp + (size_t)(2 * kp2) * ND + dgV;

    uint4 kr0, kr1, vre, vro;                   // staged regs for next K-block
    // prologue: stage block 0 into buffer 0
    kr0 = *(const uint4*)(ksrc);
    kr1 = *(const uint4*)(ksrc + 8);
    vre = *(const uint4*)(vsrc);
    vro = *(const uint4*)(vsrc + ND);
    {
        *(uint4*)&Ks[0][lane][dgK]     = kr0;
        *(uint4*)&Ks[0][lane][dgK + 8] = kr1;
        const u32* ew = (const u32*)&vre;
        const u32* ow = (const u32*)&vro;
        #pragma unroll
        for (int d = 0; d < 4; ++d) {       // v_perm_b32 pair-pack transpose
            u32 lo = __builtin_amdgcn_perm(ow[d], ew[d], 0x05040100u);
            u32 hi = __builtin_amdgcn_perm(ow[d], ew[d], 0x07060302u);
            *(u32*)&Vt[0][dgV + 2 * d][2 * kp2]     = lo;
            *(u32*)&Vt[0][dgV + 2 * d + 1][2 * kp2] = hi;
        }
    }
    __syncthreads();

    union W8 { u32 wd[4]; bf16x8 f; };

    for (int kb = 0; kb < NN / 64; ++kb) {
        const int cur = kb & 1, nxt = cur ^ 1;
        const bool more = (kb + 1) < (NN / 64);
        if (more) {   // issue next block's global loads early (hide under compute)
            const u16* ks2 = ksrc + (size_t)(kb + 1) * 64 * ND;
            kr0 = *(const uint4*)ks2;
            kr1 = *(const uint4*)(ks2 + 8);
            const u16* vs2 = vsrc + (size_t)(kb + 1) * 64 * ND;
            vre = *(const uint4*)vs2;
            vro = *(const uint4*)(vs2 + ND);
        }
        // ---- QK (s0): S^T = K . Q^T, col=lane&31=q, row=key pattern ----
        f32x16 sT0[2], sT1[2];
        __builtin_amdgcn_s_setprio(1);
        {
            bf16x8 k0 = *(const bf16x8*)&Ks[cur][m32][8 * half];
            bf16x8 k1 = *(const bf16x8*)&Ks[cur][32 + m32][8 * half];
            sT0[0] = __builtin_amdgcn_mfma_f32_32x32x16_bf16(k0, qf[0][0], z, 0, 0, 0);
            sT0[1] = __builtin_amdgcn_mfma_f32_32x32x16_bf16(k1, qf[0][0], z, 0, 0, 0);
        }
        #pragma unroll
        for (int kt = 1; kt < 4; ++kt) {
            bf16x8 k0 = *(const bf16x8*)&Ks[cur][m32][16 * kt + 8 * half];
            bf16x8 k1 = *(const bf16x8*)&Ks[cur][32 + m32][16 * kt + 8 * half];
            sT0[0] = __builtin_amdgcn_mfma_f32_32x32x16_bf16(k0, qf[0][kt], sT0[0], 0, 0, 0);
            sT0[1] = __builtin_amdgcn_mfma_f32_32x32x16_bf16(k1, qf[0][kt], sT0[1], 0, 0, 0);
        }
        // ---- QK (s1): issues while sT0 chain drains ----
        {
            bf16x8 k0 = *(const bf16x8*)&Ks[cur][m32][8 * half];
            bf16x8 k1 = *(const bf16x8*)&Ks[cur][32 + m32][8 * half];
            sT1[0] = __builtin_amdgcn_mfma_f32_32x32x16_bf16(k0, qf[1][0], z, 0, 0, 0);
            sT1[1] = __builtin_amdgcn_mfma_f32_32x32x16_bf16(k1, qf[1][0], z, 0, 0, 0);
        }
        #pragma unroll
        for (int kt = 1; kt < 4; ++kt) {
            bf16x8 k0 = *(const bf16x8*)&Ks[cur][m32][16 * kt + 8 * half];
            bf16x8 k1 = *(const bf16x8*)&Ks[cur][32 + m32][16 * kt + 8 * half];
            sT1[0] = __builtin_amdgcn_mfma_f32_32x32x16_bf16(k0, qf[1][kt], sT1[0], 0, 0, 0);
            sT1[1] = __builtin_amdgcn_mfma_f32_32x32x16_bf16(k1, qf[1][kt], sT1[1], 0, 0, 0);
        }
        __builtin_amdgcn_s_setprio(0);
        // ---- SM (s0): exp2 + cvt_pk + permlane, under QK(s1) MFMAs ----
        W8 pa0[4], pa1[4];
        {
            float ss0 = 0.f, ss1 = 0.f;
            #pragma unroll
            for (int kh = 0; kh < 2; ++kh) {
                float p[16];
                #pragma unroll
                for (int r = 0; r < 16; ++r) p[r] = fast_exp2(sT0[kh][r]);
                #pragma unroll
                for (int r = 0; r < 8; ++r) { ss0 += p[r]; ss1 += p[8 + r]; }
                u32 c[4][2];
                #pragma unroll
                for (int g = 0; g < 4; ++g) {
                    c[g][0] = pkbf(p[4 * g + 0], p[4 * g + 1]);
                    c[g][1] = pkbf(p[4 * g + 2], p[4 * g + 3]);
                }
                #pragma unroll
                for (int par = 0; par < 2; ++par) {
                    u32pair wA = swap32(c[2 * par][0], c[2 * par + 1][0]);
                    u32pair wB = swap32(c[2 * par][1], c[2 * par + 1][1]);
                    const int kt = 2 * kh + par;
                    pa0[kt].wd[0] = wA.x;   // keys +0,+1 (from low-half lane)
                    pa0[kt].wd[1] = wB.x;   // keys +2,+3
                    pa0[kt].wd[2] = wA.y;   // keys +4,+5 (from high-half lane)
                    pa0[kt].wd[3] = wB.y;   // keys +6,+7
                }
            }
            lpart[0] += ss0 + ss1;
        }
        // ---- PV (s0) ----
        __builtin_amdgcn_s_setprio(1);
        #pragma unroll
        for (int kt = 0; kt < 4; ++kt) {
            bf16x8 v0 = *(const bf16x8*)&Vt[cur][m32][16 * kt + 8 * half];
            bf16x8 v1 = *(const bf16x8*)&Vt[cur][32 + m32][16 * kt + 8 * half];
            O[0][0] = __builtin_amdgcn_mfma_f32_32x32x16_bf16(pa0[kt].f, v0, O[0][0], 0, 0, 0);
            O[0][1] = __builtin_amdgcn_mfma_f32_32x32x16_bf16(pa0[kt].f, v1, O[0][1], 0, 0, 0);
        }
        __builtin_amdgcn_s_setprio(0);
        // ---- SM (s1): under PV(s0) MFMAs ----
        {
            float ss0 = 0.f, ss1 = 0.f;
            #pragma unroll
            for (int kh = 0; kh < 2; ++kh) {
                float p[16];
                #pragma unroll
                for (int r = 0; r < 16; ++r) p[r] = fast_exp2(sT1[kh][r]);
                #pragma unroll
                for (int r = 0; r < 8; ++r) { ss0 += p[r]; ss1 += p[8 + r]; }
                u32 c[4][2];
                #pragma unroll
                for (int g = 0; g < 4; ++g) {
                    c[g][0] = pkbf(p[4 * g + 0], p[4 * g + 1]);
                    c[g][1] = pkbf(p[4 * g + 2], p[4 * g + 3]);
                }
                #pragma unroll
                for (int par = 0; par < 2; ++par) {
                    u32pair wA = swap32(c[2 * par][0], c[2 * par + 1][0]);
                    u32pair wB = swap32(c[2 * par][1], c[2 * par + 1][1]);
                    const int kt = 2 * kh + par;
                    pa1[kt].wd[0] = wA.x;
                    pa1[kt].wd[1] = wB.x;
                    pa1[kt].wd[2] = wA.y;
                    pa1[kt].wd[3] = wB.y;
                }
            }
            lpart[1] += ss0 + ss1;
        }
        // ---- PV (s1) ----
        __builtin_amdgcn_s_setprio(1);
        #pragma unroll
        for (int kt = 0; kt < 4; ++kt) {
            bf16x8 v0 = *(const bf16x8*)&Vt[cur][m32][16 * kt + 8 * half];
            bf16x8 v1 = *(const bf16x8*)&Vt[cur][32 + m32][16 * kt + 8 * half];
            O[1][0] = __builtin_amdgcn_mfma_f32_32x32x16_bf16(pa1[kt].f, v0, O[1][0], 0, 0, 0);
            O[1][1] = __builtin_amdgcn_mfma_f32_32x32x16_bf16(pa1[kt].f, v1, O[1][1], 0, 0, 0);
        }
        __builtin_amdgcn_s_setprio(0);
        // ---- stage next block into nxt buffer; ONE barrier per iteration ----
        if (more) {
            *(uint4*)&Ks[nxt][lane][dgK]     = kr0;
            *(uint4*)&Ks[nxt][lane][dgK + 8] = kr1;
            const u32* ew = (const u32*)&vre;
            const u32* ow = (const u32*)&vro;
            #pragma unroll
            for (int d = 0; d < 4; ++d) {
                u32 lo = __builtin_amdgcn_perm(ow[d], ew[d], 0x05040100u);
                u32 hi = __builtin_amdgcn_perm(ow[d], ew[d], 0x07060302u);
                *(u32*)&Vt[nxt][dgV + 2 * d][2 * kp2]     = lo;
                *(u32*)&Vt[nxt][dgV + 2 * d + 1][2 * kp2] = hi;
            }
            __syncthreads();   // nxt writes visible; cur reads done for all waves
        }
    }
    // epilogue: denominator = own half-sum + other half (lanes l, l+32 share q),
    // then redistribute to O's row layout via shfl.
    #pragma unroll
    for (int s = 0; s < 2; ++s) {
        const float tot = lpart[s] + __shfl_xor(lpart[s], 32);  // at lane l: q=l&31
        #pragma unroll
        for (int r = 0; r < 16; ++r) {
            const int qq = (r & 3) + 8 * (r >> 2) + 4 * half;   // O-row for this reg
            const float inv = 1.0f / __shfl(tot, qq);           // lane qq holds q=qq
            const int row = q0 + 32 * s + qq;
            u16* dst = aout + ((size_t)(b * NN + row)) * NC + hh * 64;
            dst[m32]      = f2bf(O[s][0][r] * inv);
            dst[32 + m32] = f2bf(O[s][1][r] * inv);
        }
    }
}

// ---------------------------------------------------------------------------
extern "C" void kernel_launch(void* const* d_in, const int* in_sizes, int n_in,
                              void* d_out, int out_size, void* d_ws, size_t ws_size,
                              hipStream_t stream) {
    const float* x     = (const float*)d_in[0];
    const float* qkv_w = (const float*)d_in[1];
    const float* qkv_b = (const float*)d_in[2];
    const float* q_nw  = (const float*)d_in[3];
    const float* q_nb  = (const float*)d_in[4];
    const float* k_nw  = (const float*)d_in[5];
    const float* k_nb  = (const float*)d_in[6];
    const float* p_w   = (const float*)d_in[7];
    const float* p_b   = (const float*)d_in[8];
    float* out = (float*)d_out;               // fp32 output
    // ws layout (u16 elements):
    //   qkv   [3][B][H][N][D]                              48 MB
    //   x_bf / attn_o (aliased: x_bf dead after QKV GEMM)  16.8 MB
    //   w_bf  qkv_w bf16                                    6.3 MB
    //   pw_bf proj_w bf16                                   2.1 MB
    u16* qkv    = (u16*)d_ws;
    u16* x_bf   = qkv + (size_t)3 * NB * NH * NN * ND;
    u16* attn_o = x_bf;                        // alias
    u16* w_bf   = x_bf + (size_t)NM * NC;
    u16* pw_bf  = w_bf + (size_t)J_QKV * NK;

    cvt_bf16<<<(NM * NC) / 2048, 256, 0, stream>>>(x, x_bf);
    cvt_bf16<<<(J_QKV * NK) / 2048, 256, 0, stream>>>(qkv_w, w_bf);
    cvt_bf16<<<(NC * NK) / 2048, 256, 0, stream>>>(p_w, pw_bf);

    // 1D grids (both % 8 == 0) with in-kernel bijective XCD-chunk swizzle.
    gemm_nt<0, J_QKV / 128><<<(J_QKV / 128) * (NM / 128), 256, 0, stream>>>(
        x_bf, w_bf, qkv_b, q_nw, q_nb, k_nw, k_nb, qkv);
    attn_mfma<<<NB * NH * (NN / 256), 256, 0, stream>>>(qkv, attn_o);
    gemm_nt<1, NC / 128><<<(NC / 128) * (NM / 128), 256, 0, stream>>>(
        attn_o, pw_bf, p_b, q_nw, q_nb, k_nw, k_nb, out);
}